// Round 8
// baseline (274.119 us; speedup 1.0000x reference)
//
#include <hip/hip_runtime.h>

// FANS: B=131072 rows x 16 states, MLP 12->64->64->1 with tanh, fp32 in/out.
// R8 = R7 resubmitted verbatim (R7 bench was an infra failure: container died
// twice before running; no kernel signal). R7 rationale:
// (from R6 @95.5us, VALU 64%, occ 33%): the bound is VALU issue with
// latency slack; two fixes:
//  1) Occupancy 4 -> 8 waves/SIMD: CHUNK=4 (grid 2048 = 8 blocks/CU),
//     __launch_bounds__(256,8) (VGPR cap 64; R6 used 56).
//  2) Cheaper tanh: fold 2*log2(e) into W0/W1 f16 fragments (MFMA emits
//     pre-scaled preacts -> tanh = exp2, add, rcp, fma: 20 cyc, no mul);
//     fold "1-2r" into the W2 dot (acc init = sum(w2), accumulate
//     fma(r, -2*w2, acc)) -> deletes 16 fma/tile.
// LDS conflicts (3.4e6, 26cyc/tile) sit on a non-saturated LDS pipe: ignored.

#define N_STATES 16
#define CHUNK    4
#define TANH_SCALE 2.885390081777927f   // 2*log2(e)

typedef _Float16 f16x8 __attribute__((ext_vector_type(8)));
typedef float    f32x4 __attribute__((ext_vector_type(4)));

__device__ __forceinline__ unsigned int pack_f16(float a, float b) {
    auto p = __builtin_amdgcn_cvt_pkrtz(a, b);          // __fp16 ext_vector(2)
    union { decltype(p) h; unsigned int u; } cv{p};
    return cv.u;
}

// input ps = 2*log2(e)*x (pre-scaled by weight fold); returns r = 1/(e^{2x}+1)
// so that tanh(x) = 1 - 2r.
__device__ __forceinline__ float sig_r(float ps) {
    float e = __builtin_amdgcn_exp2f(ps);
    return __builtin_amdgcn_rcpf(e + 1.0f);
}
__device__ __forceinline__ float tanh_from_scaled(float ps) {
    return __builtin_fmaf(-2.0f, sig_r(ps), 1.0f);
}

__global__ __launch_bounds__(256, 8) void fans_mfma_kernel(
    const float* __restrict__ x_f, const float* __restrict__ x_b,
    const float* __restrict__ u,   const float* __restrict__ W0,
    const float* __restrict__ W1,  const float* __restrict__ W2,
    float* __restrict__ out)
{
    // z planes: plane q (0/1) holds dwords [4q..4q+3] of each row's 16 f16.
    __shared__ __align__(16) uint4 zpl[2 * 256];               // 8 KB
    // H^T pair-packed, row stride 36 dwords (144B).
    __shared__ __align__(16) unsigned int Hd[4][16][36];       // 9 KB

    const int s   = blockIdx.y;
    const int tid = threadIdx.x;
    const int b0  = blockIdx.x * (256 * CHUNK);

    const int lid = tid & 63;
    const int w   = tid >> 6;     // wave id; wave w owns local rows [64w,64w+64)
    const int c   = lid & 15;
    const int q   = lid >> 4;

    // ---------------- weight fragments (once per block) ----------------
    // Layer1 A-frag: A[m = feat 16t+c][k = 8q+j] = W0[s][feat][k] * SCALE
    f16x8 a0[4];
    {
        const float* w0s = W0 + s * 768;
        #pragma unroll
        for (int t = 0; t < 4; ++t) {
            #pragma unroll
            for (int j = 0; j < 8; ++j) {
                const int k = 8 * q + j;
                const float v = (k < 12) ? w0s[(16 * t + c) * 12 + k] * TANH_SCALE : 0.0f;
                a0[t][j] = (_Float16)v;
            }
        }
    }
    // Layer2 A-frag: A[m = feat_out 16t+c][k = 32ks+8q+j] = W1[s][o][h] * SCALE
    f16x8 a1[2][4];
    {
        const float* w1s = W1 + s * 4096;
        #pragma unroll
        for (int ks = 0; ks < 2; ++ks) {
            #pragma unroll
            for (int t = 0; t < 4; ++t) {
                const float4* p = (const float4*)(w1s + (16 * t + c) * 64 + 32 * ks + 8 * q);
                const float4 v0 = p[0], v1 = p[1];
                a1[ks][t] = (f16x8){(_Float16)(v0.x * TANH_SCALE), (_Float16)(v0.y * TANH_SCALE),
                                    (_Float16)(v0.z * TANH_SCALE), (_Float16)(v0.w * TANH_SCALE),
                                    (_Float16)(v1.x * TANH_SCALE), (_Float16)(v1.y * TANH_SCALE),
                                    (_Float16)(v1.z * TANH_SCALE), (_Float16)(v1.w * TANH_SCALE)};
            }
        }
    }
    // W2 fold: dx = sum(w2) + sum_o r_o * (-2*w2_o). Lane holds feats 16t+4q+r.
    float w2n[16];
    float sumw2 = 0.0f;
    {
        const float* w2s = W2 + s * 64;
        #pragma unroll
        for (int t = 0; t < 4; ++t)
            #pragma unroll
            for (int r = 0; r < 4; ++r) {
                const float v = w2s[16 * t + 4 * q + r];
                w2n[4 * t + r] = -2.0f * v;
                sumw2 += v;
            }
    }

    const int wrap = (s > 8) ? (s - 8) : 0;   // IDX[s] = {0..wrap-1}++{s..15}

    #pragma unroll 1
    for (int ch = 0; ch < CHUNK; ++ch) {
        const int rbase = b0 + ch * 256;

        // ---- phase 1: gather z for own row, pack, 2x b128 into planes ----
        {
            const int row = rbase + tid;
            float zs[8];
            #pragma unroll
            for (int j = 0; j < 8; ++j) {
                const int idx = (j < wrap) ? j : (s + j - wrap);  // uniform
                zs[j] = (idx < 8) ? x_f[row * 8 + idx] : x_b[row * 8 + (idx - 8)];
            }
            const float4 uv = *(const float4*)(u + row * 4);
            zpl[tid] = make_uint4(pack_f16(zs[0], zs[1]), pack_f16(zs[2], zs[3]),
                                  pack_f16(zs[4], zs[5]), pack_f16(zs[6], zs[7]));
            zpl[256 + tid] = make_uint4(pack_f16(uv.x, uv.y), pack_f16(uv.z, uv.w), 0u, 0u);
        }

        // ---- phase 2: 4 M-tiles of 16 rows (own wave's rows only) ----
        #pragma unroll
        for (int m = 0; m < 4; ++m) {
            const int rowb = 64 * w + 16 * m;

            // z B-frag: B[k = 8q+j][n = row c]; quads 2,3 are zero (K pad)
            f16x8 zf = {0, 0, 0, 0, 0, 0, 0, 0};
            if (q < 2) {
                const uint4 zv = zpl[q * 256 + rowb + c];
                union { uint4 v; f16x8 h; } cz{zv};
                zf = cz.h;
            }

            // layer 1: C[row = feat 16t+4q+r][col = batch row c], pre-scaled
            f32x4 c1[4];
            #pragma unroll
            for (int t = 0; t < 4; ++t)
                c1[t] = __builtin_amdgcn_mfma_f32_16x16x32_f16(
                    a0[t], zf, (f32x4){0.f, 0.f, 0.f, 0.f}, 0, 0, 0);

            // tanh -> pack -> LDS: dword P = 8t+2q holds feats (16t+4q, +1)
            #pragma unroll
            for (int t = 0; t < 4; ++t) {
                *(uint2*)&Hd[w][c][8 * t + 2 * q] =
                    make_uint2(pack_f16(tanh_from_scaled(c1[t][0]), tanh_from_scaled(c1[t][1])),
                               pack_f16(tanh_from_scaled(c1[t][2]), tanh_from_scaled(c1[t][3])));
            }

            // layer 2: B-frag[k = 32ks+8q+j][n = c] = dwords 16ks+4q+0..3
            f32x4 c2[4] = {{0.f, 0.f, 0.f, 0.f}, {0.f, 0.f, 0.f, 0.f},
                           {0.f, 0.f, 0.f, 0.f}, {0.f, 0.f, 0.f, 0.f}};
            #pragma unroll
            for (int ks = 0; ks < 2; ++ks) {
                const uint4 hv = *(const uint4*)&Hd[w][c][16 * ks + 4 * q];
                union { uint4 v; f16x8 h; } bb{hv};
                #pragma unroll
                for (int t = 0; t < 4; ++t)
                    c2[t] = __builtin_amdgcn_mfma_f32_16x16x32_f16(a1[ks][t], bb.h, c2[t], 0, 0, 0);
            }

            // layer 3: acc = sum(w2) + sum_o r_o * (-2 w2_o); reduce over quads
            float acc = sumw2;
            #pragma unroll
            for (int t = 0; t < 4; ++t)
                #pragma unroll
                for (int r = 0; r < 4; ++r)
                    acc = __builtin_fmaf(sig_r(c2[t][r]), w2n[4 * t + r], acc);
            acc += __shfl_xor(acc, 16);
            acc += __shfl_xor(acc, 32);

            if (lid < 16)
                out[(rbase + rowb + lid) * N_STATES + s] = acc;
        }
    }
}

extern "C" void kernel_launch(void* const* d_in, const int* in_sizes, int n_in,
                              void* d_out, int out_size, void* d_ws, size_t ws_size,
                              hipStream_t stream) {
    const float* x_f = (const float*)d_in[0];
    const float* x_b = (const float*)d_in[1];
    const float* u   = (const float*)d_in[2];
    const float* W0  = (const float*)d_in[3];
    const float* W1  = (const float*)d_in[4];
    const float* W2  = (const float*)d_in[5];
    float* out = (float*)d_out;

    const int nb = in_sizes[0] / 8;                 // 131072 = 128 * 1024
    dim3 grid(nb / (256 * CHUNK), N_STATES);        // (128, 16) = 2048 blocks
    fans_mfma_kernel<<<grid, 256, 0, stream>>>(x_f, x_b, u, W0, W1, W2, out);
}

// Round 9
// 139.447 us; speedup vs baseline: 1.9658x; 1.9658x over previous
//
#include <hip/hip_runtime.h>

// FANS: B=131072 rows x 16 states, MLP 12->64->64->1 with tanh, fp32 in/out.
// R9 = R6 config + tanh folds ONLY. R8 post-mortem: __launch_bounds__(256,8)
// capped unified VGPR+AGPR at 64/wave; weight fragments alone need 64
// (a0 16 + a1 32 + w2n 16) -> allocator spilled to scratch (FETCH 573MB,
// VGPR_Count 32, HBM 43%) -> 211us. Weights-in-registers structure needs
// ~90+ unified regs -> occupancy stays 4 waves/SIMD; raising it requires a
// register diet (future experiment), not a launch-bounds decree.
// Kept from R7/R8 (validated numerically, absmax identical):
//  - 2*log2(e) folded into W0/W1 f16 fragments (no per-tanh mul)
//  - "1-2r" affine folded into W2 dot (acc init sum(w2), fma(r,-2w2))
// Config reverted to R6: CHUNK=8, launch_bounds(256,4), grid (64,16).

#define N_STATES 16
#define CHUNK    8
#define TANH_SCALE 2.885390081777927f   // 2*log2(e)

typedef _Float16 f16x8 __attribute__((ext_vector_type(8)));
typedef float    f32x4 __attribute__((ext_vector_type(4)));

__device__ __forceinline__ unsigned int pack_f16(float a, float b) {
    auto p = __builtin_amdgcn_cvt_pkrtz(a, b);          // __fp16 ext_vector(2)
    union { decltype(p) h; unsigned int u; } cv{p};
    return cv.u;
}

// input ps = 2*log2(e)*x (pre-scaled via weight fold); r = 1/(e^{2x}+1),
// tanh(x) = 1 - 2r.
__device__ __forceinline__ float sig_r(float ps) {
    float e = __builtin_amdgcn_exp2f(ps);
    return __builtin_amdgcn_rcpf(e + 1.0f);
}
__device__ __forceinline__ float tanh_from_scaled(float ps) {
    return __builtin_fmaf(-2.0f, sig_r(ps), 1.0f);
}

__global__ __launch_bounds__(256, 4) void fans_mfma_kernel(
    const float* __restrict__ x_f, const float* __restrict__ x_b,
    const float* __restrict__ u,   const float* __restrict__ W0,
    const float* __restrict__ W1,  const float* __restrict__ W2,
    float* __restrict__ out)
{
    // z planes: plane q (0/1) holds dwords [4q..4q+3] of each row's 16 f16.
    __shared__ __align__(16) uint4 zpl[2 * 256];               // 8 KB
    // H^T pair-packed, row stride 36 dwords (144B).
    __shared__ __align__(16) unsigned int Hd[4][16][36];       // 9 KB

    const int s   = blockIdx.y;
    const int tid = threadIdx.x;
    const int b0  = blockIdx.x * (256 * CHUNK);

    const int lid = tid & 63;
    const int w   = tid >> 6;     // wave id; wave w owns local rows [64w,64w+64)
    const int c   = lid & 15;
    const int q   = lid >> 4;

    // ---------------- weight fragments (once per block, amortized 8x) -------
    // Layer1 A-frag: A[m = feat 16t+c][k = 8q+j] = W0[s][feat][k] * SCALE
    f16x8 a0[4];
    {
        const float* w0s = W0 + s * 768;
        #pragma unroll
        for (int t = 0; t < 4; ++t) {
            #pragma unroll
            for (int j = 0; j < 8; ++j) {
                const int k = 8 * q + j;
                const float v = (k < 12) ? w0s[(16 * t + c) * 12 + k] * TANH_SCALE : 0.0f;
                a0[t][j] = (_Float16)v;
            }
        }
    }
    // Layer2 A-frag: A[m = feat_out 16t+c][k = 32ks+8q+j] = W1[s][o][h] * SCALE
    f16x8 a1[2][4];
    {
        const float* w1s = W1 + s * 4096;
        #pragma unroll
        for (int ks = 0; ks < 2; ++ks) {
            #pragma unroll
            for (int t = 0; t < 4; ++t) {
                const float4* p = (const float4*)(w1s + (16 * t + c) * 64 + 32 * ks + 8 * q);
                const float4 v0 = p[0], v1 = p[1];
                a1[ks][t] = (f16x8){(_Float16)(v0.x * TANH_SCALE), (_Float16)(v0.y * TANH_SCALE),
                                    (_Float16)(v0.z * TANH_SCALE), (_Float16)(v0.w * TANH_SCALE),
                                    (_Float16)(v1.x * TANH_SCALE), (_Float16)(v1.y * TANH_SCALE),
                                    (_Float16)(v1.z * TANH_SCALE), (_Float16)(v1.w * TANH_SCALE)};
            }
        }
    }
    // W2 fold: dx = sum(w2) + sum_o r_o * (-2*w2_o). Lane holds feats 16t+4q+r.
    float w2n[16];
    float sumw2 = 0.0f;
    {
        const float* w2s = W2 + s * 64;
        #pragma unroll
        for (int t = 0; t < 4; ++t)
            #pragma unroll
            for (int r = 0; r < 4; ++r) {
                const float v = w2s[16 * t + 4 * q + r];
                w2n[4 * t + r] = -2.0f * v;
                sumw2 += v;
            }
    }

    const int wrap = (s > 8) ? (s - 8) : 0;   // IDX[s] = {0..wrap-1}++{s..15}

    #pragma unroll 1
    for (int ch = 0; ch < CHUNK; ++ch) {
        const int rbase = b0 + ch * 256;

        // ---- phase 1: gather z for own row, pack, 2x b128 into planes ----
        {
            const int row = rbase + tid;
            float zs[8];
            #pragma unroll
            for (int j = 0; j < 8; ++j) {
                const int idx = (j < wrap) ? j : (s + j - wrap);  // uniform
                zs[j] = (idx < 8) ? x_f[row * 8 + idx] : x_b[row * 8 + (idx - 8)];
            }
            const float4 uv = *(const float4*)(u + row * 4);
            zpl[tid] = make_uint4(pack_f16(zs[0], zs[1]), pack_f16(zs[2], zs[3]),
                                  pack_f16(zs[4], zs[5]), pack_f16(zs[6], zs[7]));
            zpl[256 + tid] = make_uint4(pack_f16(uv.x, uv.y), pack_f16(uv.z, uv.w), 0u, 0u);
        }

        // ---- phase 2: 4 M-tiles of 16 rows (own wave's rows only) ----
        #pragma unroll
        for (int m = 0; m < 4; ++m) {
            const int rowb = 64 * w + 16 * m;

            // z B-frag: B[k = 8q+j][n = row c]; quads 2,3 are zero (K pad)
            f16x8 zf = {0, 0, 0, 0, 0, 0, 0, 0};
            if (q < 2) {
                const uint4 zv = zpl[q * 256 + rowb + c];
                union { uint4 v; f16x8 h; } cz{zv};
                zf = cz.h;
            }

            // layer 1: C[row = feat 16t+4q+r][col = batch row c], pre-scaled
            f32x4 c1[4];
            #pragma unroll
            for (int t = 0; t < 4; ++t)
                c1[t] = __builtin_amdgcn_mfma_f32_16x16x32_f16(
                    a0[t], zf, (f32x4){0.f, 0.f, 0.f, 0.f}, 0, 0, 0);

            // tanh -> pack -> LDS: dword P = 8t+2q holds feats (16t+4q, +1)
            #pragma unroll
            for (int t = 0; t < 4; ++t) {
                *(uint2*)&Hd[w][c][8 * t + 2 * q] =
                    make_uint2(pack_f16(tanh_from_scaled(c1[t][0]), tanh_from_scaled(c1[t][1])),
                               pack_f16(tanh_from_scaled(c1[t][2]), tanh_from_scaled(c1[t][3])));
            }

            // layer 2: B-frag[k = 32ks+8q+j][n = c] = dwords 16ks+4q+0..3
            f32x4 c2[4] = {{0.f, 0.f, 0.f, 0.f}, {0.f, 0.f, 0.f, 0.f},
                           {0.f, 0.f, 0.f, 0.f}, {0.f, 0.f, 0.f, 0.f}};
            #pragma unroll
            for (int ks = 0; ks < 2; ++ks) {
                const uint4 hv = *(const uint4*)&Hd[w][c][16 * ks + 4 * q];
                union { uint4 v; f16x8 h; } bb{hv};
                #pragma unroll
                for (int t = 0; t < 4; ++t)
                    c2[t] = __builtin_amdgcn_mfma_f32_16x16x32_f16(a1[ks][t], bb.h, c2[t], 0, 0, 0);
            }

            // layer 3: acc = sum(w2) + sum_o r_o * (-2 w2_o); reduce over quads
            float acc = sumw2;
            #pragma unroll
            for (int t = 0; t < 4; ++t)
                #pragma unroll
                for (int r = 0; r < 4; ++r)
                    acc = __builtin_fmaf(sig_r(c2[t][r]), w2n[4 * t + r], acc);
            acc += __shfl_xor(acc, 16);
            acc += __shfl_xor(acc, 32);

            if (lid < 16)
                out[(rbase + rowb + lid) * N_STATES + s] = acc;
        }
    }
}

extern "C" void kernel_launch(void* const* d_in, const int* in_sizes, int n_in,
                              void* d_out, int out_size, void* d_ws, size_t ws_size,
                              hipStream_t stream) {
    const float* x_f = (const float*)d_in[0];
    const float* x_b = (const float*)d_in[1];
    const float* u   = (const float*)d_in[2];
    const float* W0  = (const float*)d_in[3];
    const float* W1  = (const float*)d_in[4];
    const float* W2  = (const float*)d_in[5];
    float* out = (float*)d_out;

    const int nb = in_sizes[0] / 8;                 // 131072 = 64 * 2048
    dim3 grid(nb / (256 * CHUNK), N_STATES);        // (64, 16) = 1024 blocks
    fans_mfma_kernel<<<grid, 256, 0, stream>>>(x_f, x_b, u, W0, W1, W2, out);
}